// Round 1
// baseline (377.145 us; speedup 1.0000x reference)
//
#include <hip/hip_runtime.h>
#include <hip/hip_bf16.h>
#include <cstdint>

#define AS1 __attribute__((address_space(1)))
#define AS3 __attribute__((address_space(3)))

typedef __bf16 bf16x8 __attribute__((ext_vector_type(8)));
typedef float  f32x16 __attribute__((ext_vector_type(16)));

__device__ __forceinline__ void gld_lds16(const void* g, void* l) {
    __builtin_amdgcn_global_load_lds((const AS1 void*)g, (AS3 void*)l, 16, 0, 0);
}

// ---------------- Kernel 0: rotated 3x3 kernels (exact fp32 replica), ONCE ----------------
__global__ void k_rot(const float* __restrict__ base, float* __restrict__ w1) {
    int m = threadIdx.x;            // 0..127 = g*16+o
    int g = m >> 4, o = m & 15;
    float th = 6.28318530717958647692f * (float)g / 8.0f;
    float c = cosf(th), s = sinf(th);
    for (int i = 0; i < 3; ++i) {
        float ys = (2.0f * i + 1.0f) / 3.0f - 1.0f;
        for (int j = 0; j < 3; ++j) {
            float xs = (2.0f * j + 1.0f) / 3.0f - 1.0f;
            float gx = c * xs - s * ys;
            float gy = s * xs + c * ys;
            float px = ((gx + 1.0f) * 3.0f - 1.0f) * 0.5f;
            float py = ((gy + 1.0f) * 3.0f - 1.0f) * 0.5f;
            float x0 = floorf(px), y0 = floorf(py);
            float wx = px - x0, wy = py - y0;
            int x0i = (int)x0, y0i = (int)y0;
            auto gat = [&](int yi, int xi) -> float {
                bool v = (yi >= 0) && (yi < 3) && (xi >= 0) && (xi < 3);
                int yc = min(max(yi, 0), 2), xc = min(max(xi, 0), 2);
                return v ? base[o * 9 + yc * 3 + xc] : 0.0f;
            };
            w1[m * 9 + i * 3 + j] =
                  gat(y0i, x0i)         * (1.0f - wx) * (1.0f - wy)
                + gat(y0i, x0i + 1)     * wx          * (1.0f - wy)
                + gat(y0i + 1, x0i)     * (1.0f - wx) * wy
                + gat(y0i + 1, x0i + 1) * wx          * wy;
        }
    }
}

// ---------------- Kernel 1: conv1 + relu -> channel-last padded bf16 h ----------------
// Loads precomputed w1. Blocks <1152 also build the bf16 GEMM A matrix.
// hl layout: [b][yy 0..29][xx 0..29][c 0..127], borders = 0.
__global__ __launch_bounds__(256) void k_conv1(const float* __restrict__ x,
                                               const float* __restrict__ w1g,
                                               const float* __restrict__ w2,
                                               __hip_bfloat16* __restrict__ hl,
                                               __hip_bfloat16* __restrict__ A) {
    int tid = threadIdx.x;

    if (blockIdx.x < 1152) {
        int i = blockIdx.x * 256 + tid;
        int r = i / 1152, k = i - r * 1152;
        int g = r >> 5, o2 = r & 31;
        int kk = k >> 7, cch = k & 127;
        int ky = kk / 3, kx = kk - ky * 3;
        int c2 = cch >> 3, hh = cch & 7;
        int gi = (g - hh) & 7;
        A[i] = __float2bfloat16(w2[((o2 * 16 + c2) * 8 + gi) * 9 + ky * 3 + kx]);
    }

    __shared__ float w1s[1152];
    for (int i = tid; i < 1152; i += 256) w1s[i] = w1g[i];
    __syncthreads();

    const int c0 = (tid & 15) * 8;
    float wreg[8][9];
#pragma unroll
    for (int cc = 0; cc < 8; ++cc)
#pragma unroll
        for (int k = 0; k < 9; ++k) wreg[cc][k] = w1s[(c0 + cc) * 9 + k];

    const int slot = tid >> 4;                    // 0..15
    const int band = blockIdx.x % 15;
    const int b    = blockIdx.x / 15;
    const int yy   = band * 2 + (slot >> 3);      // padded row 0..29
    const int xx0  = (slot & 7) * 4;              // 0,4,...,28

    const float* xb = x + b * 784;
    float xv[3][6];
#pragma unroll
    for (int t = 0; t < 3; ++t) {
        int sy = yy - 2 + t;
        bool syok = (sy >= 0) && (sy < 28);
#pragma unroll
        for (int u = 0; u < 6; ++u) {
            int sx = xx0 - 2 + u;
            bool ok = syok && (sx >= 0) && (sx < 28);
            xv[t][u] = ok ? xb[sy * 28 + sx] : 0.0f;
        }
    }

    float acc[4][8];
#pragma unroll
    for (int j = 0; j < 4; ++j)
#pragma unroll
        for (int cc = 0; cc < 8; ++cc) acc[j][cc] = 0.0f;

#pragma unroll
    for (int t = 0; t < 3; ++t)
#pragma unroll
        for (int u = 0; u < 3; ++u) {
#pragma unroll
            for (int j = 0; j < 4; ++j) {
                float xvv = xv[t][j + u];
#pragma unroll
                for (int cc = 0; cc < 8; ++cc)
                    acc[j][cc] += xvv * wreg[cc][t * 3 + u];
            }
        }

#pragma unroll
    for (int j = 0; j < 4; ++j) {
        int xx = xx0 + j;
        if (xx < 30) {
            bool interior = (yy >= 1) && (yy <= 28) && (xx >= 1) && (xx <= 28);
            union { __hip_bfloat16 h[8]; float4 f4; } u;
#pragma unroll
            for (int cc = 0; cc < 8; ++cc)
                u.h[cc] = __float2bfloat16(interior ? fmaxf(acc[j][cc], 0.0f) : 0.0f);
            int pi = b * 900 + yy * 30 + xx;
            *(float4*)(hl + (size_t)pi * 128 + c0) = u.f4;
        }
    }
}

// ---------------- Kernel 2: conv2 implicit GEMM — 256x256 tile, 8-phase pipeline ----
// BM=256 (all of M), BN=256, BK=64 (18 K-tiles). 512 threads = 8 waves.
// Each phase computes ONE 128x128 C-quadrant (all 8 waves inside it, wave = 64x32),
// so a phase touches exactly one (A-half, B-half) pair. Double-buffered 128 KiB LDS;
// stage the 4 half-tiles of K-tile t+1 during tile t's 4 phases (order A0,B0,B1,A1);
// counted s_waitcnt vmcnt(4) — never vmcnt(0) in the main loop. Raw s_barrier (no
// __syncthreads -> no vmcnt(0) drain). A-frags reused across the 2 phases sharing an
// A-half; B1-frags reused across phases 1-2 (LDS traffic 224KB/K-tile < MFMA time).
// Per 64KB buffer: Ah0 @0 | Ah1 @16384 | Bh0 @32768 | Bh1 @49152.
// Each 16KB half-tile: [ch 0..15][row rl=ch*8+(lane>>3)][8 x 16B, col XOR-swizzled
// by (rl&7)^(ch&3)] — linear gld_lds dest + pre-swizzled global source (proven
// conflict-free in the previous kernel).
__global__ __launch_bounds__(512, 2) void k_conv2(const __hip_bfloat16* __restrict__ A,
                                                  const __hip_bfloat16* __restrict__ hl,
                                                  __hip_bfloat16* __restrict__ p) {
    __shared__ __align__(16) char smem[131072];

    const int tid  = threadIdx.x;
    const int lane = tid & 63;
    const int w    = tid >> 6;          // 0..7
    const int hi   = lane >> 5;
    const int wqr  = w >> 2;            // 0..1  M-pos within quadrant
    const int wqc  = w & 3;             // 0..3  N-pos within quadrant

    const int bid = blockIdx.x;         // grid 1568 = 8 * 196
    const int nt  = (bid & 7) * 196 + (bid >> 3);   // bijective XCD swizzle
    const int n0  = nt << 8;            // 256 N per tile

    // ---- staging addresses: wave w stages ch = 2w+q of each 16KB half-tile ----
    uint32_t aSrc[2], bSrc[2][2], ldsCh[2];
#pragma unroll
    for (int q = 0; q < 2; ++q) {
        int ch = 2 * w + q;
        int rl = ch * 8 + (lane >> 3);                 // row within 128-row half
        int ca = (lane & 7) ^ (rl & 7) ^ (ch & 3);     // pre-swizzled 16B column
        aSrc[q]  = (uint32_t)(rl * 2304 + ca * 16);    // + hm*294912 + s*128
        ldsCh[q] = (uint32_t)(ch * 1024);
#pragma unroll
        for (int hn = 0; hn < 2; ++hn) {
            int n = n0 + hn * 128 + rl;
            int b = n / 784; int rr = n - b * 784;
            int y = rr / 28; int xx = rr - y * 28;
            bSrc[q][hn] = (uint32_t)(((b * 30 + y) * 30 + xx) * 256 + ca * 16); // + boff(s)
        }
    }

    // ---- fragment read addresses ----
    uint32_t aRow[2]; int aSwz[2];
#pragma unroll
    for (int i = 0; i < 2; ++i) {
        int r = wqr * 64 + i * 32 + (lane & 31);
        aRow[i] = (uint32_t)(r * 128);
        aSwz[i] = (r & 7) ^ ((r >> 3) & 3);
    }
    const int rB = wqc * 32 + (lane & 31);
    const uint32_t bRow = (uint32_t)(rB * 128);
    const int bSwz = (rB & 7) ^ ((rB >> 3) & 3);

    f32x16 acc[4][2];
#pragma unroll
    for (int pq = 0; pq < 4; ++pq)
#pragma unroll
        for (int i = 0; i < 2; ++i) acc[pq][i] = (f32x16)(0.0f);

    const char* Ab = (const char*)A;
    const char* Hb = (const char*)hl;

    // ---- prologue: stage tile 0 -> buf0, order A0, B0, B1, A1 (boff(0)=0) ----
    gld_lds16(Ab + aSrc[0], smem + ldsCh[0]);
    gld_lds16(Ab + aSrc[1], smem + ldsCh[1]);
    gld_lds16(Hb + bSrc[0][0], smem + 32768 + ldsCh[0]);
    gld_lds16(Hb + bSrc[1][0], smem + 32768 + ldsCh[1]);
    gld_lds16(Hb + bSrc[0][1], smem + 49152 + ldsCh[0]);
    gld_lds16(Hb + bSrc[1][1], smem + 49152 + ldsCh[1]);
    gld_lds16(Ab + aSrc[0] + 294912, smem + 16384 + ldsCh[0]);
    gld_lds16(Ab + aSrc[1] + 294912, smem + 16384 + ldsCh[1]);
    asm volatile("s_waitcnt vmcnt(4)" ::: "memory");   // A0,B0 of tile0 landed
    asm volatile("s_barrier" ::: "memory");

#pragma unroll 1
    for (int t = 0; t < 17; ++t) {
        const uint32_t cb = (uint32_t)((t & 1) << 16);
        const uint32_t cn = cb ^ 65536u;
        const uint32_t aoffn = (uint32_t)((t + 1) * 128);
        const int kkn = (t + 1) >> 1;
        const int kyn = kkn / 3;
        const int kxn = kkn - kyn * 3;
        const uint32_t boffn = (uint32_t)((kyn * 30 + kxn) * 256 + ((t + 1) & 1) * 128);

        const char* SA0 = smem + cb;
        const char* SA1 = smem + cb + 16384;
        const char* SB0 = smem + cb + 32768;
        const char* SB1 = smem + cb + 49152;

        bf16x8 a0[4], a1[4], bv[4];

        // ---- phase 0: quadrant (0,0); stage A-half0 of t+1 ----
#pragma unroll
        for (int k = 0; k < 4; ++k) {
            const uint32_t c0 = (uint32_t)(k * 2 + hi);
            a0[k] = *(const bf16x8*)(SA0 + aRow[0] + ((c0 ^ (uint32_t)aSwz[0]) << 4));
            a1[k] = *(const bf16x8*)(SA0 + aRow[1] + ((c0 ^ (uint32_t)aSwz[1]) << 4));
            bv[k] = *(const bf16x8*)(SB0 + bRow    + ((c0 ^ (uint32_t)bSwz ) << 4));
        }
        gld_lds16(Ab + aSrc[0] + aoffn, smem + cn + ldsCh[0]);
        gld_lds16(Ab + aSrc[1] + aoffn, smem + cn + ldsCh[1]);
        asm volatile("s_barrier" ::: "memory");
        __builtin_amdgcn_s_setprio(1);
#pragma unroll
        for (int k = 0; k < 4; ++k) {
            acc[0][0] = __builtin_amdgcn_mfma_f32_32x32x16_bf16(a0[k], bv[k], acc[0][0], 0, 0, 0);
            acc[0][1] = __builtin_amdgcn_mfma_f32_32x32x16_bf16(a1[k], bv[k], acc[0][1], 0, 0, 0);
        }
        __builtin_amdgcn_sched_barrier(0);
        __builtin_amdgcn_s_setprio(0);
        asm volatile("s_waitcnt vmcnt(4)" ::: "memory");   // B1 of tile t landed
        asm volatile("s_barrier" ::: "memory");

        // ---- phase 1: quadrant (0,1) — a0/a1 reused; stage B-half0 of t+1 ----
#pragma unroll
        for (int k = 0; k < 4; ++k) {
            const uint32_t c0 = (uint32_t)(k * 2 + hi);
            bv[k] = *(const bf16x8*)(SB1 + bRow + ((c0 ^ (uint32_t)bSwz) << 4));
        }
        gld_lds16(Hb + bSrc[0][0] + boffn, smem + cn + 32768 + ldsCh[0]);
        gld_lds16(Hb + bSrc[1][0] + boffn, smem + cn + 32768 + ldsCh[1]);
        asm volatile("s_barrier" ::: "memory");
        __builtin_amdgcn_s_setprio(1);
#pragma unroll
        for (int k = 0; k < 4; ++k) {
            acc[1][0] = __builtin_amdgcn_mfma_f32_32x32x16_bf16(a0[k], bv[k], acc[1][0], 0, 0, 0);
            acc[1][1] = __builtin_amdgcn_mfma_f32_32x32x16_bf16(a1[k], bv[k], acc[1][1], 0, 0, 0);
        }
        __builtin_amdgcn_sched_barrier(0);
        __builtin_amdgcn_s_setprio(0);
        asm volatile("s_waitcnt vmcnt(4)" ::: "memory");   // A1 of tile t landed
        asm volatile("s_barrier" ::: "memory");

        // ---- phase 2: quadrant (1,1) — bv reused; stage B-half1 of t+1 ----
#pragma unroll
        for (int k = 0; k < 4; ++k) {
            const uint32_t c0 = (uint32_t)(k * 2 + hi);
            a0[k] = *(const bf16x8*)(SA1 + aRow[0] + ((c0 ^ (uint32_t)aSwz[0]) << 4));
            a1[k] = *(const bf16x8*)(SA1 + aRow[1] + ((c0 ^ (uint32_t)aSwz[1]) << 4));
        }
        gld_lds16(Hb + bSrc[0][1] + boffn, smem + cn + 49152 + ldsCh[0]);
        gld_lds16(Hb + bSrc[1][1] + boffn, smem + cn + 49152 + ldsCh[1]);
        asm volatile("s_barrier" ::: "memory");
        __builtin_amdgcn_s_setprio(1);
#pragma unroll
        for (int k = 0; k < 4; ++k) {
            acc[2][0] = __builtin_amdgcn_mfma_f32_32x32x16_bf16(a0[k], bv[k], acc[2][0], 0, 0, 0);
            acc[2][1] = __builtin_amdgcn_mfma_f32_32x32x16_bf16(a1[k], bv[k], acc[2][1], 0, 0, 0);
        }
        __builtin_amdgcn_sched_barrier(0);
        __builtin_amdgcn_s_setprio(0);
        asm volatile("s_barrier" ::: "memory");            // no wait: phase 3 needs nothing new

        // ---- phase 3: quadrant (1,0) — a0/a1 reused; stage A-half1 of t+1 ----
#pragma unroll
        for (int k = 0; k < 4; ++k) {
            const uint32_t c0 = (uint32_t)(k * 2 + hi);
            bv[k] = *(const bf16x8*)(SB0 + bRow + ((c0 ^ (uint32_t)bSwz) << 4));
        }
        gld_lds16(Ab + aSrc[0] + aoffn + 294912, smem + cn + 16384 + ldsCh[0]);
        gld_lds16(Ab + aSrc[1] + aoffn + 294912, smem + cn + 16384 + ldsCh[1]);
        asm volatile("s_barrier" ::: "memory");
        __builtin_amdgcn_s_setprio(1);
#pragma unroll
        for (int k = 0; k < 4; ++k) {
            acc[3][0] = __builtin_amdgcn_mfma_f32_32x32x16_bf16(a0[k], bv[k], acc[3][0], 0, 0, 0);
            acc[3][1] = __builtin_amdgcn_mfma_f32_32x32x16_bf16(a1[k], bv[k], acc[3][1], 0, 0, 0);
        }
        __builtin_amdgcn_sched_barrier(0);
        __builtin_amdgcn_s_setprio(0);
        asm volatile("s_waitcnt vmcnt(4)" ::: "memory");   // A0,B0 of t+1 landed
        asm volatile("s_barrier" ::: "memory");
    }

    // ---- drain: tile 17 from buf1, no staging ----
    {
        const char* SA0 = smem + 65536;
        const char* SA1 = smem + 65536 + 16384;
        const char* SB0 = smem + 65536 + 32768;
        const char* SB1 = smem + 65536 + 49152;
        bf16x8 a0[4], a1[4], bv[4];

        // phase 0 (0,0)
#pragma unroll
        for (int k = 0; k < 4; ++k) {
            const uint32_t c0 = (uint32_t)(k * 2 + hi);
            a0[k] = *(const bf16x8*)(SA0 + aRow[0] + ((c0 ^ (uint32_t)aSwz[0]) << 4));
            a1[k] = *(const bf16x8*)(SA0 + aRow[1] + ((c0 ^ (uint32_t)aSwz[1]) << 4));
            bv[k] = *(const bf16x8*)(SB0 + bRow + ((c0 ^ (uint32_t)bSwz) << 4));
        }
#pragma unroll
        for (int k = 0; k < 4; ++k) {
            acc[0][0] = __builtin_amdgcn_mfma_f32_32x32x16_bf16(a0[k], bv[k], acc[0][0], 0, 0, 0);
            acc[0][1] = __builtin_amdgcn_mfma_f32_32x32x16_bf16(a1[k], bv[k], acc[0][1], 0, 0, 0);
        }
        asm volatile("s_waitcnt vmcnt(2)" ::: "memory");   // B1 of tile 17 landed
        asm volatile("s_barrier" ::: "memory");

        // phase 1 (0,1)
#pragma unroll
        for (int k = 0; k < 4; ++k) {
            const uint32_t c0 = (uint32_t)(k * 2 + hi);
            bv[k] = *(const bf16x8*)(SB1 + bRow + ((c0 ^ (uint32_t)bSwz) << 4));
        }
#pragma unroll
        for (int k = 0; k < 4; ++k) {
            acc[1][0] = __builtin_amdgcn_mfma_f32_32x32x16_bf16(a0[k], bv[k], acc[1][0], 0, 0, 0);
            acc[1][1] = __builtin_amdgcn_mfma_f32_32x32x16_bf16(a1[k], bv[k], acc[1][1], 0, 0, 0);
        }
        asm volatile("s_waitcnt vmcnt(0)" ::: "memory");   // A1 of tile 17 landed
        asm volatile("s_barrier" ::: "memory");

        // phase 2 (1,1) — bv reused
#pragma unroll
        for (int k = 0; k < 4; ++k) {
            const uint32_t c0 = (uint32_t)(k * 2 + hi);
            a0[k] = *(const bf16x8*)(SA1 + aRow[0] + ((c0 ^ (uint32_t)aSwz[0]) << 4));
            a1[k] = *(const bf16x8*)(SA1 + aRow[1] + ((c0 ^ (uint32_t)aSwz[1]) << 4));
        }
#pragma unroll
        for (int k = 0; k < 4; ++k) {
            acc[2][0] = __builtin_amdgcn_mfma_f32_32x32x16_bf16(a0[k], bv[k], acc[2][0], 0, 0, 0);
            acc[2][1] = __builtin_amdgcn_mfma_f32_32x32x16_bf16(a1[k], bv[k], acc[2][1], 0, 0, 0);
        }

        // phase 3 (1,0) — a0/a1 reused
#pragma unroll
        for (int k = 0; k < 4; ++k) {
            const uint32_t c0 = (uint32_t)(k * 2 + hi);
            bv[k] = *(const bf16x8*)(SB0 + bRow + ((c0 ^ (uint32_t)bSwz) << 4));
        }
#pragma unroll
        for (int k = 0; k < 4; ++k) {
            acc[3][0] = __builtin_amdgcn_mfma_f32_32x32x16_bf16(a0[k], bv[k], acc[3][0], 0, 0, 0);
            acc[3][1] = __builtin_amdgcn_mfma_f32_32x32x16_bf16(a1[k], bv[k], acc[3][1], 0, 0, 0);
        }
    }

    // ---- epilogue: relu + mean over 8 consecutive M-rows; bf16 store ----
    const int QMarr[4] = {0, 0, 1, 1};
    const int QNarr[4] = {0, 1, 1, 0};
#pragma unroll
    for (int pq = 0; pq < 4; ++pq) {
#pragma unroll
        for (int i = 0; i < 2; ++i) {
            f32x16 v = acc[pq][i];
#pragma unroll
            for (int u = 0; u < 4; ++u) {
                float sv = fmaxf(v[4*u], 0.0f) + fmaxf(v[4*u+1], 0.0f)
                         + fmaxf(v[4*u+2], 0.0f) + fmaxf(v[4*u+3], 0.0f);
                sv += __shfl_xor(sv, 32, 64);
                if (hi == 0) {
                    int a = QMarr[pq] * 16 + wqr * 8 + i * 4 + u;
                    int n = n0 + QNarr[pq] * 128 + wqc * 32 + (lane & 31);
                    int b = n / 784; int rr = n - b * 784;
                    p[(b * 32 + a) * 784 + rr] = __float2bfloat16(sv * 0.125f);
                }
            }
        }
    }
}

// ---------------- Kernel 3: FC — 4-way k-split, bf16 p reads ----------------
__global__ __launch_bounds__(256) void k_fc(const __hip_bfloat16* __restrict__ p,
                                            const float* __restrict__ fw,
                                            const float* __restrict__ fb,
                                            float* __restrict__ out) {
    int b = blockIdx.x >> 2, ks = blockIdx.x & 3;
    int tid = threadIdx.x;
    const bf16x8* pb = (const bf16x8*)(p + (size_t)b * 25088);
    const float4* w4 = (const float4*)fw;
    float acc[10] = {};
    for (int t = ks * 784 + tid; t < (ks + 1) * 784; t += 256) {
        union { bf16x8 v; __hip_bfloat16 h[8]; } u;
        u.v = pb[t];
        float vf[8];
#pragma unroll
        for (int e = 0; e < 8; ++e) vf[e] = __bfloat162float(u.h[e]);
#pragma unroll
        for (int c = 0; c < 10; ++c) {
            float4 u0 = w4[c * 6272 + 2 * t];
            float4 u1 = w4[c * 6272 + 2 * t + 1];
            acc[c] += vf[0] * u0.x + vf[1] * u0.y + vf[2] * u0.z + vf[3] * u0.w
                    + vf[4] * u1.x + vf[5] * u1.y + vf[6] * u1.z + vf[7] * u1.w;
        }
    }
    __shared__ float red[10][4];
    int lane = tid & 63, wv = tid >> 6;
#pragma unroll
    for (int c = 0; c < 10; ++c) {
        float s = acc[c];
#pragma unroll
        for (int o = 32; o > 0; o >>= 1) s += __shfl_down(s, o, 64);
        if (lane == 0) red[c][wv] = s;
    }
    __syncthreads();
    if (tid < 10) {
        float s = red[tid][0] + red[tid][1] + red[tid][2] + red[tid][3];
        if (ks == 0) s += fb[tid];
        atomicAdd(&out[b * 10 + tid], s);
    }
}

// ---------------- launch ----------------
extern "C" void kernel_launch(void* const* d_in, const int* in_sizes, int n_in,
                              void* d_out, int out_size, void* d_ws, size_t ws_size,
                              hipStream_t stream) {
    const float* x  = (const float*)d_in[0];
    const float* bw = (const float*)d_in[1];
    const float* w2 = (const float*)d_in[2];
    const float* fw = (const float*)d_in[3];
    const float* fb = (const float*)d_in[4];
    float* out = (float*)d_out;
    char* ws = (char*)d_ws;

    float*          w1   = (float*)(ws);
    __hip_bfloat16* Amat = (__hip_bfloat16*)(ws + 4608);
    __hip_bfloat16* hl   = (__hip_bfloat16*)(ws + 594432);
    __hip_bfloat16* p    = (__hip_bfloat16*)(ws + 118563328);

    hipMemsetAsync(d_out, 0, (size_t)out_size * sizeof(float), stream);
    k_rot  <<<1,    128, 0, stream>>>(bw, w1);
    k_conv1<<<7680, 256, 0, stream>>>(x, w1, w2, hl, Amat);
    k_conv2<<<1568, 512, 0, stream>>>(Amat, hl, p);
    k_fc   <<<2048, 256, 0, stream>>>(p, fw, fb, out);
}